// Round 3
// baseline (3552.913 us; speedup 1.0000x reference)
//
#include <hip/hip_runtime.h>
#include <hip/hip_bf16.h>

typedef __hip_bfloat16 bf16;
typedef __attribute__((ext_vector_type(8))) short short8;
typedef __attribute__((ext_vector_type(4))) float floatx4;

#define N_BATCH 16
#define NBQ 56
#define SEQ (NBQ*NBQ)          // 3136
#define DIM 384
#define DI 768
#define MROWS (N_BATCH*SEQ)    // 50176

__device__ __forceinline__ float b2f(bf16 v){ return __bfloat162float(v); }
__device__ __forceinline__ bf16 f2b(float v){ return __float2bfloat16(v); }

// dual-dtype input load / output store (flag: 1 = fp32 tensors, 0 = bf16)
__device__ __forceinline__ float ldin(const void* p, size_t i, int f32){
    return f32 ? ((const float*)p)[i] : __bfloat162float(((const bf16*)p)[i]);
}
__device__ __forceinline__ void stout(void* p, size_t i, int f32, float v){
    if (f32) ((float*)p)[i] = v; else ((bf16*)p)[i] = __float2bfloat16(v);
}

__device__ __forceinline__ void gl2lds16(const void* g, void* l) {
    __builtin_amdgcn_global_load_lds((const __attribute__((address_space(1))) void*)g,
                                     (__attribute__((address_space(3))) void*)l, 16, 0, 0);
}

// ---------------- dtype detection: bf16-NaN patterns only occur if data is fp32 ----------------
__global__ void detect_kernel(const unsigned short* __restrict__ x, int* __restrict__ flag) {
    __shared__ int cnt;
    if (threadIdx.x == 0) cnt = 0;
    __syncthreads();
    int c = 0;
    for (int i = threadIdx.x; i < 16384; i += 256) {
        unsigned short u = x[i];
        if ((u & 0x7F80) == 0x7F80) ++c;   // bf16 exp==0xFF (inf/NaN)
    }
    if (c) atomicAdd(&cnt, c);
    __syncthreads();
    if (threadIdx.x == 0) *flag = cnt ? 1 : 0;
}

// ---------------- LayerNorm: one wave per row of 384; dual-dtype in, bf16 out ----------------
__global__ __launch_bounds__(64) void ln_kernel(const void* __restrict__ x,
        const void* __restrict__ w, const void* __restrict__ b,
        bf16* __restrict__ y, size_t row_off, const int* __restrict__ flag) {
    const int f32 = *flag;
    const size_t row = row_off + blockIdx.x;
    const int lane = threadIdx.x;
    float v[6]; float s = 0.f;
    #pragma unroll
    for (int j = 0; j < 6; ++j) { v[j] = ldin(x, row*DIM + lane + j*64, f32); s += v[j]; }
    #pragma unroll
    for (int o = 32; o; o >>= 1) s += __shfl_xor(s, o);
    const float mu = s * (1.f/DIM);
    float s2 = 0.f;
    #pragma unroll
    for (int j = 0; j < 6; ++j) { float d = v[j]-mu; s2 += d*d; }
    #pragma unroll
    for (int o = 32; o; o >>= 1) s2 += __shfl_xor(s2, o);
    const float inv = rsqrtf(s2*(1.f/DIM) + 1e-5f);
    bf16* yr = y + (size_t)blockIdx.x * DIM;   // chunk-local output row
    #pragma unroll
    for (int j = 0; j < 6; ++j) {
        int c = lane + j*64;
        yr[c] = f2b((v[j]-mu)*inv*ldin(w, c, f32) + ldin(b, c, f32));
    }
}

// ---------------- depthwise 3x3 conv on chunk-local bf16 tokens ----------------
__global__ __launch_bounds__(128) void dwconv_kernel(const bf16* __restrict__ h,
        const void* __restrict__ w, const void* __restrict__ bias,
        bf16* __restrict__ out, const int* __restrict__ flag) {
    const int f32 = *flag;
    const int c = blockIdx.x*128 + threadIdx.x;   // 0..383
    const int l = blockIdx.y;                     // 0..3135
    const int n = blockIdx.z;                     // chunk-local batch
    const int i = l / NBQ, j = l - (l / NBQ) * NBQ;
    float acc = ldin(bias, c, f32);
    const bf16* hn = h + (size_t)n*SEQ*DIM;
    #pragma unroll
    for (int di = 0; di < 3; ++di) {
        int ii = i + di - 1;
        if (ii < 0 || ii >= NBQ) continue;
        #pragma unroll
        for (int dj = 0; dj < 3; ++dj) {
            int jj = j + dj - 1;
            if (jj < 0 || jj >= NBQ) continue;
            acc += b2f(hn[((size_t)(ii*NBQ + jj))*DIM + c]) * ldin(w, c*9 + di*3 + dj, f32);
        }
    }
    out[((size_t)n*SEQ + l)*DIM + c] = f2b(acc);
}

// ---------------- minGRU linear recurrence scan, chunk-local, in-place over hid ----------------
__global__ __launch_bounds__(64) void scan_kernel(bf16* __restrict__ G, int dir) {
    const int c = blockIdx.x*64 + threadIdx.x;  // 0..767
    bf16* base = G + (size_t)blockIdx.y*SEQ*(2*DI) + c;
    float h = 0.f;
    if (dir == 0) {
        #pragma unroll 4
        for (int t = 0; t < SEQ; ++t) {
            bf16* p = base + (size_t)t*(2*DI);
            float hid = b2f(p[0]), gate = b2f(p[DI]);
            float z  = 1.f/(1.f + __expf(-gate));
            float tl = hid >= 0.f ? hid + 0.5f : 1.f/(1.f + __expf(-hid));
            h = (1.f - z)*h + z*tl;
            p[0] = f2b(h);
        }
    } else {
        #pragma unroll 4
        for (int t = SEQ-1; t >= 0; --t) {
            bf16* p = base + (size_t)t*(2*DI);
            float hid = b2f(p[0]), gate = b2f(p[DI]);
            float z  = 1.f/(1.f + __expf(-gate));
            float tl = hid >= 0.f ? hid + 0.5f : 1.f/(1.f + __expf(-hid));
            h = (1.f - z)*h + z*tl;
            p[0] = f2b(h);
        }
    }
}

// ---------------- small weight transpose: dual-dtype in, bf16 out ----------------
__global__ void transpose_kernel(const void* __restrict__ src, bf16* __restrict__ dst,
                                 int R, int C, const int* __restrict__ flag) {
    const int f32 = *flag;
    int idx = blockIdx.x*256 + threadIdx.x;
    if (idx >= R*C) return;
    int r = idx / C, c = idx - r*C;
    dst[(size_t)c*R + r] = f2b(ldin(src, idx, f32));
}

// ---------------- 128x128 bf16 MFMA GEMM, Bt is N x K row-major ----------------
// MODE 0: store bf16 (internal); 1: +resid -> dual out; 2: +bias, gelu -> bf16 (internal);
// MODE 3: +bias +resid -> dual out
template<int MODE>
__global__ __launch_bounds__(256, 2) void gemm_kernel(
        const bf16* __restrict__ A, int lda,
        const bf16* __restrict__ Bt,
        void* __restrict__ C, int ldc, int K, size_t row_off,
        const void* __restrict__ bias, const void* __restrict__ resid,
        const int* __restrict__ flag) {
    __shared__ __align__(16) short lsA[128*64];
    __shared__ __align__(16) short lsB[128*64];
    const int tid  = threadIdx.x;
    const int tn0  = blockIdx.x * 128;
    const int tm0  = blockIdx.y * 128;
    const int lane = tid & 63;
    const int wave = tid >> 6;
    const int wm = (wave & 1) * 64;
    const int wn = (wave >> 1) * 64;
    const int row16 = lane & 15;
    const int quad  = lane >> 4;

    floatx4 acc[4][4];
    #pragma unroll
    for (int i = 0; i < 4; ++i)
        #pragma unroll
        for (int j = 0; j < 4; ++j)
            acc[i][j] = (floatx4){0.f, 0.f, 0.f, 0.f};

    for (int k0 = 0; k0 < K; k0 += 64) {
        const char* Ab = (const char*)(A + (size_t)tm0*lda + k0);
        const char* Bb = (const char*)(Bt + (size_t)tn0*K + k0);
        #pragma unroll
        for (int it = 0; it < 4; ++it) {
            int o = it*4096 + tid*16;
            int row = o >> 7, cb = o & 127;
            gl2lds16(Ab + (size_t)row*((size_t)lda*2) + cb, (char*)lsA + o);
        }
        #pragma unroll
        for (int it = 0; it < 4; ++it) {
            int o = it*4096 + tid*16;
            int row = o >> 7, cb = o & 127;
            gl2lds16(Bb + (size_t)row*((size_t)K*2) + cb, (char*)lsB + o);
        }
        __syncthreads();
        #pragma unroll
        for (int kk = 0; kk < 64; kk += 32) {
            short8 af[4], bfr[4];
            #pragma unroll
            for (int i = 0; i < 4; ++i)
                af[i] = *(const short8*)(lsA + (wm + i*16 + row16)*64 + kk + quad*8);
            #pragma unroll
            for (int j = 0; j < 4; ++j)
                bfr[j] = *(const short8*)(lsB + (wn + j*16 + row16)*64 + kk + quad*8);
            #pragma unroll
            for (int i = 0; i < 4; ++i)
                #pragma unroll
                for (int j = 0; j < 4; ++j)
                    acc[i][j] = __builtin_amdgcn_mfma_f32_16x16x32_bf16(af[i], bfr[j], acc[i][j], 0, 0, 0);
        }
        __syncthreads();
    }

    const int f32 = (MODE == 0) ? 0 : *flag;
    #pragma unroll
    for (int i = 0; i < 4; ++i) {
        #pragma unroll
        for (int j = 0; j < 4; ++j) {
            #pragma unroll
            for (int r = 0; r < 4; ++r) {
                const int gm = tm0 + wm + i*16 + quad*4 + r;
                const int gn = tn0 + wn + j*16 + row16;
                float v = acc[i][j][r];
                if (MODE == 0) {
                    ((bf16*)C)[(size_t)gm*ldc + gn] = f2b(v);
                } else if (MODE == 1) {
                    size_t gi = (row_off + gm)*(size_t)ldc + gn;
                    v += ldin(resid, gi, f32);
                    stout(C, gi, f32, v);
                } else if (MODE == 2) {
                    v += ldin(bias, gn, f32);
                    v = 0.5f*v*(1.f + erff(v*0.70710678118f));
                    ((bf16*)C)[(size_t)gm*ldc + gn] = f2b(v);
                } else {
                    size_t gi = (row_off + gm)*(size_t)ldc + gn;
                    v += ldin(bias, gn, f32) + ldin(resid, gi, f32);
                    stout(C, gi, f32, v);
                }
            }
        }
    }
}

extern "C" void kernel_launch(void* const* d_in, const int* in_sizes, int n_in,
                              void* d_out, int out_size, void* d_ws, size_t ws_size,
                              hipStream_t stream) {
    const void* x       = d_in[0];
    const void* norm_w  = d_in[1];
    const void* norm_b  = d_in[2];
    const void* dw_w    = d_in[3];
    const void* dw_b    = d_in[4];
    const void* whg1    = d_in[5];
    const void* wout1   = d_in[6];
    const void* whg2    = d_in[7];
    const void* wout2   = d_in[8];
    const void* norm2_w = d_in[9];
    const void* norm2_b = d_in[10];
    const void* p1_w    = d_in[11];
    const void* p1_b    = d_in[12];
    const void* p2_w    = d_in[13];
    const void* p2_b    = d_in[14];
    void* out = d_out;
    char* ws = (char*)d_ws;

    const size_t WSZ = 5898240;   // transposed weights (bf16)

    // chunk size: fit [flag|weights|h_ln_c|h_conv_c|Gbuf] in ws_size
    int CH = 16;
    for (;;) {
        size_t need = 256 + WSZ + (size_t)CH * SEQ * 4608;  // 2*(384+384+1536) bytes/row... = CH*SEQ*(2*384*2 + 1536*2)
        if (need <= ws_size || CH == 2) break;
        CH >>= 1;
    }
    const int NC = N_BATCH / CH;
    const int CHROWS = CH * SEQ;

    int* flag = (int*)ws;
    char* wb = ws + 256;
    bf16* WhgT1  = (bf16*)(wb);                  // 1536 x 384
    bf16* WhgT2  = (bf16*)(wb + 1179648);        // 1536 x 384
    bf16* WoutT1 = (bf16*)(wb + 2359296);        // 384 x 768
    bf16* WoutT2 = (bf16*)(wb + 2949120);        // 384 x 768
    bf16* P1T    = (bf16*)(wb + 3538944);        // 1536 x 384
    bf16* P2T    = (bf16*)(wb + 4718592);        // 384 x 1536
    char* dyn = ws + 256 + WSZ;
    bf16* h_ln_c   = (bf16*)(dyn);
    bf16* h_conv_c = (bf16*)(dyn + (size_t)CHROWS*DIM*2);
    bf16* Gbuf     = (bf16*)(dyn + 2*(size_t)CHROWS*DIM*2);
    bf16* mid_ln_c = h_ln_c;

    // --- dtype detection ---
    detect_kernel<<<1, 256, 0, stream>>>((const unsigned short*)x, flag);

    // --- weight prep (tiny) ---
    transpose_kernel<<<(384*1536+255)/256, 256, 0, stream>>>(whg1, WhgT1, 384, 1536, flag);
    transpose_kernel<<<(384*1536+255)/256, 256, 0, stream>>>(whg2, WhgT2, 384, 1536, flag);
    transpose_kernel<<<(768*384+255)/256, 256, 0, stream>>>(wout1, WoutT1, 768, 384, flag);
    transpose_kernel<<<(768*384+255)/256, 256, 0, stream>>>(wout2, WoutT2, 768, 384, flag);
    transpose_kernel<<<(384*1536+255)/256, 256, 0, stream>>>(p1_w, P1T, 384, 1536, flag);
    transpose_kernel<<<(1536*384+255)/256, 256, 0, stream>>>(p2_w, P2T, 1536, 384, flag);

    // --- bidirectional minGRU, one direction per pass; LN+conv recomputed per chunk ---
    for (int pass = 0; pass < 2; ++pass) {
        const bf16* WhgT  = pass ? WhgT2  : WhgT1;
        const bf16* WoutT = pass ? WoutT2 : WoutT1;
        for (int ck = 0; ck < NC; ++ck) {
            const size_t roff = (size_t)ck * CHROWS;
            ln_kernel<<<CHROWS, 64, 0, stream>>>(x, norm_w, norm_b, h_ln_c, roff, flag);
            dwconv_kernel<<<dim3(3, SEQ, CH), 128, 0, stream>>>(h_ln_c, dw_w, dw_b, h_conv_c, flag);
            // Gbuf = h_conv_c @ whg : M=CHROWS, N=1536, K=384
            gemm_kernel<0><<<dim3(1536/128, CHROWS/128), 256, 0, stream>>>(
                h_conv_c, DIM, WhgT, Gbuf, 2*DI, DIM, 0, nullptr, nullptr, flag);
            scan_kernel<<<dim3(12, CH), 64, 0, stream>>>(Gbuf, pass);
            // out[chunk] = E @ wout + resid : N=384, K=768
            const void* resid = pass ? (const void*)out : x;
            gemm_kernel<1><<<dim3(DIM/128, CHROWS/128), 256, 0, stream>>>(
                Gbuf, 2*DI, WoutT, out, DIM, DI, roff, nullptr, resid, flag);
        }
    }

    // --- LN2 + MLP, chunked ---
    for (int ck = 0; ck < NC; ++ck) {
        const size_t roff = (size_t)ck * CHROWS;
        ln_kernel<<<CHROWS, 64, 0, stream>>>(out, norm2_w, norm2_b, mid_ln_c, roff, flag);
        // Gbuf = gelu(mid_ln_c @ p1_w + p1_b) : N=1536, K=384
        gemm_kernel<2><<<dim3(1536/128, CHROWS/128), 256, 0, stream>>>(
            mid_ln_c, DIM, P1T, Gbuf, 1536, DIM, 0, p1_b, nullptr, flag);
        // out[chunk] = Gbuf @ p2_w + p2_b + out[chunk] : N=384, K=1536
        gemm_kernel<3><<<dim3(DIM/128, CHROWS/128), 256, 0, stream>>>(
            Gbuf, 1536, P2T, out, DIM, 1536, roff, p2_b, out, flag);
    }
}

// Round 4
// 1323.334 us; speedup vs baseline: 2.6848x; 2.6848x over previous
//
#include <hip/hip_runtime.h>
#include <hip/hip_bf16.h>

typedef __hip_bfloat16 bf16;
typedef __attribute__((ext_vector_type(8))) short short8;
typedef __attribute__((ext_vector_type(4))) float floatx4;

#define N_BATCH 16
#define NBQ 56
#define SEQ (NBQ*NBQ)          // 3136
#define DIM 384
#define DI 768
#define MROWS (N_BATCH*SEQ)    // 50176
#define NSEG 49
#define SEGLEN 64

__device__ __forceinline__ float b2f(bf16 v){ return __bfloat162float(v); }
__device__ __forceinline__ bf16 f2b(float v){ return __float2bfloat16(v); }

// dual-dtype input load / output store (flag: 1 = fp32 tensors, 0 = bf16)
__device__ __forceinline__ float ldin(const void* p, size_t i, int f32){
    return f32 ? ((const float*)p)[i] : __bfloat162float(((const bf16*)p)[i]);
}
__device__ __forceinline__ void stout(void* p, size_t i, int f32, float v){
    if (f32) ((float*)p)[i] = v; else ((bf16*)p)[i] = __float2bfloat16(v);
}

__device__ __forceinline__ void gl2lds16(const void* g, void* l) {
    __builtin_amdgcn_global_load_lds((const __attribute__((address_space(1))) void*)g,
                                     (__attribute__((address_space(3))) void*)l, 16, 0, 0);
}

// ---------------- dtype detection: bf16-NaN patterns only occur if data is fp32 ----------------
__global__ void detect_kernel(const unsigned short* __restrict__ x, int* __restrict__ flag) {
    __shared__ int cnt;
    if (threadIdx.x == 0) cnt = 0;
    __syncthreads();
    int c = 0;
    for (int i = threadIdx.x; i < 16384; i += 256) {
        unsigned short u = x[i];
        if ((u & 0x7F80) == 0x7F80) ++c;   // bf16 exp==0xFF (inf/NaN)
    }
    if (c) atomicAdd(&cnt, c);
    __syncthreads();
    if (threadIdx.x == 0) *flag = cnt ? 1 : 0;
}

// ---------------- LayerNorm: one wave per row of 384; dual-dtype in, bf16 out ----------------
__global__ __launch_bounds__(64) void ln_kernel(const void* __restrict__ x,
        const void* __restrict__ w, const void* __restrict__ b,
        bf16* __restrict__ y, size_t row_off, const int* __restrict__ flag) {
    const int f32 = *flag;
    const size_t row = row_off + blockIdx.x;
    const int lane = threadIdx.x;
    float v[6]; float s = 0.f;
    #pragma unroll
    for (int j = 0; j < 6; ++j) { v[j] = ldin(x, row*DIM + lane + j*64, f32); s += v[j]; }
    #pragma unroll
    for (int o = 32; o; o >>= 1) s += __shfl_xor(s, o);
    const float mu = s * (1.f/DIM);
    float s2 = 0.f;
    #pragma unroll
    for (int j = 0; j < 6; ++j) { float d = v[j]-mu; s2 += d*d; }
    #pragma unroll
    for (int o = 32; o; o >>= 1) s2 += __shfl_xor(s2, o);
    const float inv = rsqrtf(s2*(1.f/DIM) + 1e-5f);
    bf16* yr = y + (size_t)blockIdx.x * DIM;   // chunk-local output row
    #pragma unroll
    for (int j = 0; j < 6; ++j) {
        int c = lane + j*64;
        yr[c] = f2b((v[j]-mu)*inv*ldin(w, c, f32) + ldin(b, c, f32));
    }
}

// ---------------- depthwise 3x3 conv on chunk-local bf16 tokens ----------------
__global__ __launch_bounds__(128) void dwconv_kernel(const bf16* __restrict__ h,
        const void* __restrict__ w, const void* __restrict__ bias,
        bf16* __restrict__ out, const int* __restrict__ flag) {
    const int f32 = *flag;
    const int c = blockIdx.x*128 + threadIdx.x;   // 0..383
    const int l = blockIdx.y;                     // 0..3135
    const int n = blockIdx.z;                     // chunk-local batch
    const int i = l / NBQ, j = l - (l / NBQ) * NBQ;
    float acc = ldin(bias, c, f32);
    const bf16* hn = h + (size_t)n*SEQ*DIM;
    #pragma unroll
    for (int di = 0; di < 3; ++di) {
        int ii = i + di - 1;
        if (ii < 0 || ii >= NBQ) continue;
        #pragma unroll
        for (int dj = 0; dj < 3; ++dj) {
            int jj = j + dj - 1;
            if (jj < 0 || jj >= NBQ) continue;
            acc += b2f(hn[((size_t)(ii*NBQ + jj))*DIM + c]) * ldin(w, c*9 + di*3 + dj, f32);
        }
    }
    out[((size_t)n*SEQ + l)*DIM + c] = f2b(acc);
}

// ---------------- segmented minGRU scan ----------------
// h_t = a_t*h_{t-1} + b_t ; a = 1-z, b = z*tl. Logical step u: t = dir ? SEQ-1-u : u.
// Phase 1: per-segment composition (A_s, B_s) in fp32.
__global__ __launch_bounds__(64) void scan_p1(const bf16* __restrict__ G,
        float* __restrict__ Aseg, float* __restrict__ Bseg, int dir) {
    const int c = blockIdx.x*64 + threadIdx.x;   // 0..767
    const int s = blockIdx.y;                    // 0..48
    const int n = blockIdx.z;
    const bf16* base = G + (size_t)n*SEQ*(2*DI) + c;
    float A = 1.f, B = 0.f;
    #pragma unroll 4
    for (int u = 0; u < SEGLEN; ++u) {
        const int t = dir ? (SEQ-1 - (s*SEGLEN + u)) : (s*SEGLEN + u);
        const bf16* p = base + (size_t)t*(2*DI);
        float hid = b2f(p[0]), gate = b2f(p[DI]);
        float z  = 1.f/(1.f + __expf(-gate));
        float tl = hid >= 0.f ? hid + 0.5f : 1.f/(1.f + __expf(-hid));
        float a = 1.f - z;
        A *= a;
        B = a*B + z*tl;
    }
    const size_t idx = ((size_t)n*NSEG + s)*DI + c;
    Aseg[idx] = A; Bseg[idx] = B;
}

// Phase 2: exclusive scan over segments -> segment start states P_s (h before segment s).
__global__ __launch_bounds__(64) void scan_p2(const float* __restrict__ Aseg,
        const float* __restrict__ Bseg, float* __restrict__ Pseg) {
    const int c = blockIdx.x*64 + threadIdx.x;
    const int n = blockIdx.y;
    float P = 0.f;
    for (int s = 0; s < NSEG; ++s) {
        const size_t idx = ((size_t)n*NSEG + s)*DI + c;
        Pseg[idx] = P;
        P = Aseg[idx]*P + Bseg[idx];
    }
}

// Phase 3: re-scan each segment from P_s, write h over hid slot (bf16).
__global__ __launch_bounds__(64) void scan_p3(bf16* __restrict__ G,
        const float* __restrict__ Pseg, int dir) {
    const int c = blockIdx.x*64 + threadIdx.x;
    const int s = blockIdx.y;
    const int n = blockIdx.z;
    bf16* base = G + (size_t)n*SEQ*(2*DI) + c;
    float h = Pseg[((size_t)n*NSEG + s)*DI + c];
    #pragma unroll 4
    for (int u = 0; u < SEGLEN; ++u) {
        const int t = dir ? (SEQ-1 - (s*SEGLEN + u)) : (s*SEGLEN + u);
        bf16* p = base + (size_t)t*(2*DI);
        float hid = b2f(p[0]), gate = b2f(p[DI]);
        float z  = 1.f/(1.f + __expf(-gate));
        float tl = hid >= 0.f ? hid + 0.5f : 1.f/(1.f + __expf(-hid));
        h = (1.f - z)*h + z*tl;
        p[0] = f2b(h);
    }
}

// ---------------- small weight transpose: dual-dtype in, bf16 out ----------------
__global__ void transpose_kernel(const void* __restrict__ src, bf16* __restrict__ dst,
                                 int R, int C, const int* __restrict__ flag) {
    const int f32 = *flag;
    int idx = blockIdx.x*256 + threadIdx.x;
    if (idx >= R*C) return;
    int r = idx / C, c = idx - r*C;
    dst[(size_t)c*R + r] = f2b(ldin(src, idx, f32));
}

// ---------------- 128x128 bf16 MFMA GEMM, Bt is N x K row-major ----------------
// MODE 0: store bf16 (internal); 1: +resid -> dual out; 2: +bias, gelu -> bf16 (internal);
// MODE 3: +bias +resid -> dual out
template<int MODE>
__global__ __launch_bounds__(256, 2) void gemm_kernel(
        const bf16* __restrict__ A, int lda,
        const bf16* __restrict__ Bt,
        void* __restrict__ C, int ldc, int K, size_t row_off,
        const void* __restrict__ bias, const void* __restrict__ resid,
        const int* __restrict__ flag) {
    __shared__ __align__(16) short lsA[128*64];
    __shared__ __align__(16) short lsB[128*64];
    const int tid  = threadIdx.x;
    const int tn0  = blockIdx.x * 128;
    const int tm0  = blockIdx.y * 128;
    const int lane = tid & 63;
    const int wave = tid >> 6;
    const int wm = (wave & 1) * 64;
    const int wn = (wave >> 1) * 64;
    const int row16 = lane & 15;
    const int quad  = lane >> 4;

    floatx4 acc[4][4];
    #pragma unroll
    for (int i = 0; i < 4; ++i)
        #pragma unroll
        for (int j = 0; j < 4; ++j)
            acc[i][j] = (floatx4){0.f, 0.f, 0.f, 0.f};

    for (int k0 = 0; k0 < K; k0 += 64) {
        const char* Ab = (const char*)(A + (size_t)tm0*lda + k0);
        const char* Bb = (const char*)(Bt + (size_t)tn0*K + k0);
        #pragma unroll
        for (int it = 0; it < 4; ++it) {
            int o = it*4096 + tid*16;
            int row = o >> 7, cb = o & 127;
            gl2lds16(Ab + (size_t)row*((size_t)lda*2) + cb, (char*)lsA + o);
        }
        #pragma unroll
        for (int it = 0; it < 4; ++it) {
            int o = it*4096 + tid*16;
            int row = o >> 7, cb = o & 127;
            gl2lds16(Bb + (size_t)row*((size_t)K*2) + cb, (char*)lsB + o);
        }
        __syncthreads();
        #pragma unroll
        for (int kk = 0; kk < 64; kk += 32) {
            short8 af[4], bfr[4];
            #pragma unroll
            for (int i = 0; i < 4; ++i)
                af[i] = *(const short8*)(lsA + (wm + i*16 + row16)*64 + kk + quad*8);
            #pragma unroll
            for (int j = 0; j < 4; ++j)
                bfr[j] = *(const short8*)(lsB + (wn + j*16 + row16)*64 + kk + quad*8);
            #pragma unroll
            for (int i = 0; i < 4; ++i)
                #pragma unroll
                for (int j = 0; j < 4; ++j)
                    acc[i][j] = __builtin_amdgcn_mfma_f32_16x16x32_bf16(af[i], bfr[j], acc[i][j], 0, 0, 0);
        }
        __syncthreads();
    }

    const int f32 = (MODE == 0) ? 0 : *flag;
    #pragma unroll
    for (int i = 0; i < 4; ++i) {
        #pragma unroll
        for (int j = 0; j < 4; ++j) {
            #pragma unroll
            for (int r = 0; r < 4; ++r) {
                const int gm = tm0 + wm + i*16 + quad*4 + r;
                const int gn = tn0 + wn + j*16 + row16;
                float v = acc[i][j][r];
                if (MODE == 0) {
                    ((bf16*)C)[(size_t)gm*ldc + gn] = f2b(v);
                } else if (MODE == 1) {
                    size_t gi = (row_off + gm)*(size_t)ldc + gn;
                    v += ldin(resid, gi, f32);
                    stout(C, gi, f32, v);
                } else if (MODE == 2) {
                    v += ldin(bias, gn, f32);
                    v = 0.5f*v*(1.f + erff(v*0.70710678118f));
                    ((bf16*)C)[(size_t)gm*ldc + gn] = f2b(v);
                } else {
                    size_t gi = (row_off + gm)*(size_t)ldc + gn;
                    v += ldin(bias, gn, f32) + ldin(resid, gi, f32);
                    stout(C, gi, f32, v);
                }
            }
        }
    }
}

extern "C" void kernel_launch(void* const* d_in, const int* in_sizes, int n_in,
                              void* d_out, int out_size, void* d_ws, size_t ws_size,
                              hipStream_t stream) {
    const void* x       = d_in[0];
    const void* norm_w  = d_in[1];
    const void* norm_b  = d_in[2];
    const void* dw_w    = d_in[3];
    const void* dw_b    = d_in[4];
    const void* whg1    = d_in[5];
    const void* wout1   = d_in[6];
    const void* whg2    = d_in[7];
    const void* wout2   = d_in[8];
    const void* norm2_w = d_in[9];
    const void* norm2_b = d_in[10];
    const void* p1_w    = d_in[11];
    const void* p1_b    = d_in[12];
    const void* p2_w    = d_in[13];
    const void* p2_b    = d_in[14];
    void* out = d_out;
    char* ws = (char*)d_ws;

    const size_t WSZ = 5898240;   // transposed weights (bf16)

    // chunk size: fit [flag|weights|h_ln_c|h_conv_c|Gbuf] in ws_size
    int CH = 16;
    for (;;) {
        size_t need = 256 + WSZ + (size_t)CH * SEQ * 4608;
        if (need <= ws_size || CH == 2) break;
        CH >>= 1;
    }
    const int NC = N_BATCH / CH;
    const int CHROWS = CH * SEQ;

    int* flag = (int*)ws;
    char* wb = ws + 256;
    bf16* WhgT1  = (bf16*)(wb);                  // 1536 x 384
    bf16* WhgT2  = (bf16*)(wb + 1179648);        // 1536 x 384
    bf16* WoutT1 = (bf16*)(wb + 2359296);        // 384 x 768
    bf16* WoutT2 = (bf16*)(wb + 2949120);        // 384 x 768
    bf16* P1T    = (bf16*)(wb + 3538944);        // 1536 x 384
    bf16* P2T    = (bf16*)(wb + 4718592);        // 384 x 1536
    char* dyn = ws + 256 + WSZ;
    bf16* h_ln_c   = (bf16*)(dyn);
    bf16* h_conv_c = (bf16*)(dyn + (size_t)CHROWS*DIM*2);
    bf16* Gbuf     = (bf16*)(dyn + 2*(size_t)CHROWS*DIM*2);
    bf16* mid_ln_c = h_ln_c;
    // scan side buffers alias the (dead-during-scan) h_ln_c region:
    // need 3 * CH*NSEG*DI*4 bytes <= CHROWS*DIM*2  (3*0.15MB*CH vs 2.4MB*CH) ✓
    float* Aseg = (float*)h_ln_c;
    float* Bseg = Aseg + (size_t)CH*NSEG*DI;
    float* Pseg = Bseg + (size_t)CH*NSEG*DI;

    // --- dtype detection ---
    detect_kernel<<<1, 256, 0, stream>>>((const unsigned short*)x, flag);

    // --- weight prep (tiny) ---
    transpose_kernel<<<(384*1536+255)/256, 256, 0, stream>>>(whg1, WhgT1, 384, 1536, flag);
    transpose_kernel<<<(384*1536+255)/256, 256, 0, stream>>>(whg2, WhgT2, 384, 1536, flag);
    transpose_kernel<<<(768*384+255)/256, 256, 0, stream>>>(wout1, WoutT1, 768, 384, flag);
    transpose_kernel<<<(768*384+255)/256, 256, 0, stream>>>(wout2, WoutT2, 768, 384, flag);
    transpose_kernel<<<(384*1536+255)/256, 256, 0, stream>>>(p1_w, P1T, 384, 1536, flag);
    transpose_kernel<<<(1536*384+255)/256, 256, 0, stream>>>(p2_w, P2T, 1536, 384, flag);

    // --- bidirectional minGRU, one direction per pass ---
    for (int pass = 0; pass < 2; ++pass) {
        const bf16* WhgT  = pass ? WhgT2  : WhgT1;
        const bf16* WoutT = pass ? WoutT2 : WoutT1;
        for (int ck = 0; ck < NC; ++ck) {
            const size_t roff = (size_t)ck * CHROWS;
            // with NC==1 h_conv_c from pass 0 is still valid in pass 1
            if (pass == 0 || NC > 1) {
                ln_kernel<<<CHROWS, 64, 0, stream>>>(x, norm_w, norm_b, h_ln_c, roff, flag);
                dwconv_kernel<<<dim3(3, SEQ, CH), 128, 0, stream>>>(h_ln_c, dw_w, dw_b, h_conv_c, flag);
            }
            // Gbuf = h_conv_c @ whg : M=CHROWS, N=1536, K=384
            gemm_kernel<0><<<dim3(1536/128, CHROWS/128), 256, 0, stream>>>(
                h_conv_c, DIM, WhgT, Gbuf, 2*DI, DIM, 0, nullptr, nullptr, flag);
            // segmented scan (fwd or bwd), in-place over hid columns
            scan_p1<<<dim3(12, NSEG, CH), 64, 0, stream>>>(Gbuf, Aseg, Bseg, pass);
            scan_p2<<<dim3(12, CH), 64, 0, stream>>>(Aseg, Bseg, Pseg);
            scan_p3<<<dim3(12, NSEG, CH), 64, 0, stream>>>(Gbuf, Pseg, pass);
            // out[chunk] = E @ wout + resid : N=384, K=768
            const void* resid = pass ? (const void*)out : x;
            gemm_kernel<1><<<dim3(DIM/128, CHROWS/128), 256, 0, stream>>>(
                Gbuf, 2*DI, WoutT, out, DIM, DI, roff, nullptr, resid, flag);
        }
    }

    // --- LN2 + MLP, chunked ---
    for (int ck = 0; ck < NC; ++ck) {
        const size_t roff = (size_t)ck * CHROWS;
        ln_kernel<<<CHROWS, 64, 0, stream>>>(out, norm2_w, norm2_b, mid_ln_c, roff, flag);
        // Gbuf = gelu(mid_ln_c @ p1_w + p1_b) : N=1536, K=384
        gemm_kernel<2><<<dim3(1536/128, CHROWS/128), 256, 0, stream>>>(
            mid_ln_c, DIM, P1T, Gbuf, 1536, DIM, 0, p1_b, nullptr, flag);
        // out[chunk] = Gbuf @ p2_w + p2_b + out[chunk] : N=384, K=1536
        gemm_kernel<3><<<dim3(DIM/128, CHROWS/128), 256, 0, stream>>>(
            Gbuf, 1536, P2T, out, DIM, 1536, roff, p2_b, out, flag);
    }
}

// Round 5
// 1267.345 us; speedup vs baseline: 2.8034x; 1.0442x over previous
//
#include <hip/hip_runtime.h>
#include <hip/hip_bf16.h>

typedef __hip_bfloat16 bf16;
typedef __attribute__((ext_vector_type(8))) short short8;
typedef __attribute__((ext_vector_type(4))) float floatx4;

#define N_BATCH 16
#define NBQ 56
#define SEQ (NBQ*NBQ)          // 3136
#define DIM 384
#define DI 768
#define MROWS (N_BATCH*SEQ)    // 50176
#define NSEG 49
#define SEGLEN 64

__device__ __forceinline__ float b2f(bf16 v){ return __bfloat162float(v); }
__device__ __forceinline__ bf16 f2b(float v){ return __float2bfloat16(v); }

// dual-dtype input load / output store (flag: 1 = fp32 tensors, 0 = bf16)
__device__ __forceinline__ float ldin(const void* p, size_t i, int f32){
    return f32 ? ((const float*)p)[i] : __bfloat162float(((const bf16*)p)[i]);
}
__device__ __forceinline__ void stout(void* p, size_t i, int f32, float v){
    if (f32) ((float*)p)[i] = v; else ((bf16*)p)[i] = __float2bfloat16(v);
}

__device__ __forceinline__ void gl2lds16(const void* g, void* l) {
    __builtin_amdgcn_global_load_lds((const __attribute__((address_space(1))) void*)g,
                                     (__attribute__((address_space(3))) void*)l, 16, 0, 0);
}

// ---------------- dtype detection: bf16-NaN patterns only occur if data is fp32 ----------------
__global__ void detect_kernel(const unsigned short* __restrict__ x, int* __restrict__ flag) {
    __shared__ int cnt;
    if (threadIdx.x == 0) cnt = 0;
    __syncthreads();
    int c = 0;
    for (int i = threadIdx.x; i < 16384; i += 256) {
        unsigned short u = x[i];
        if ((u & 0x7F80) == 0x7F80) ++c;   // bf16 exp==0xFF (inf/NaN)
    }
    if (c) atomicAdd(&cnt, c);
    __syncthreads();
    if (threadIdx.x == 0) *flag = cnt ? 1 : 0;
}

// ---------------- LayerNorm: one wave per row of 384; dual-dtype in, bf16 out ----------------
__global__ __launch_bounds__(64) void ln_kernel(const void* __restrict__ x,
        const void* __restrict__ w, const void* __restrict__ b,
        bf16* __restrict__ y, size_t row_off, const int* __restrict__ flag) {
    const int f32 = *flag;
    const size_t row = row_off + blockIdx.x;
    const int lane = threadIdx.x;
    float v[6]; float s = 0.f;
    #pragma unroll
    for (int j = 0; j < 6; ++j) { v[j] = ldin(x, row*DIM + lane + j*64, f32); s += v[j]; }
    #pragma unroll
    for (int o = 32; o; o >>= 1) s += __shfl_xor(s, o);
    const float mu = s * (1.f/DIM);
    float s2 = 0.f;
    #pragma unroll
    for (int j = 0; j < 6; ++j) { float d = v[j]-mu; s2 += d*d; }
    #pragma unroll
    for (int o = 32; o; o >>= 1) s2 += __shfl_xor(s2, o);
    const float inv = rsqrtf(s2*(1.f/DIM) + 1e-5f);
    bf16* yr = y + (size_t)blockIdx.x * DIM;   // chunk-local output row
    #pragma unroll
    for (int j = 0; j < 6; ++j) {
        int c = lane + j*64;
        yr[c] = f2b((v[j]-mu)*inv*ldin(w, c, f32) + ldin(b, c, f32));
    }
}

// ---------------- depthwise 3x3 conv on chunk-local bf16 tokens ----------------
__global__ __launch_bounds__(128) void dwconv_kernel(const bf16* __restrict__ h,
        const void* __restrict__ w, const void* __restrict__ bias,
        bf16* __restrict__ out, const int* __restrict__ flag) {
    const int f32 = *flag;
    const int c = blockIdx.x*128 + threadIdx.x;   // 0..383
    const int l = blockIdx.y;                     // 0..3135
    const int n = blockIdx.z;                     // chunk-local batch
    const int i = l / NBQ, j = l - (l / NBQ) * NBQ;
    float acc = ldin(bias, c, f32);
    const bf16* hn = h + (size_t)n*SEQ*DIM;
    #pragma unroll
    for (int di = 0; di < 3; ++di) {
        int ii = i + di - 1;
        if (ii < 0 || ii >= NBQ) continue;
        #pragma unroll
        for (int dj = 0; dj < 3; ++dj) {
            int jj = j + dj - 1;
            if (jj < 0 || jj >= NBQ) continue;
            acc += b2f(hn[((size_t)(ii*NBQ + jj))*DIM + c]) * ldin(w, c*9 + di*3 + dj, f32);
        }
    }
    out[((size_t)n*SEQ + l)*DIM + c] = f2b(acc);
}

// ---------------- segmented minGRU scan ----------------
// h_t = a_t*h_{t-1} + b_t ; a = 1-z, b = z*tl. Logical step u: t = dir ? SEQ-1-u : u.
__global__ __launch_bounds__(64) void scan_p1(const bf16* __restrict__ G,
        float* __restrict__ Aseg, float* __restrict__ Bseg, int dir) {
    const int c = blockIdx.x*64 + threadIdx.x;   // 0..767
    const int s = blockIdx.y;                    // 0..48
    const int n = blockIdx.z;
    const bf16* base = G + (size_t)n*SEQ*(2*DI) + c;
    float A = 1.f, B = 0.f;
    #pragma unroll 4
    for (int u = 0; u < SEGLEN; ++u) {
        const int t = dir ? (SEQ-1 - (s*SEGLEN + u)) : (s*SEGLEN + u);
        const bf16* p = base + (size_t)t*(2*DI);
        float hid = b2f(p[0]), gate = b2f(p[DI]);
        float z  = 1.f/(1.f + __expf(-gate));
        float tl = hid >= 0.f ? hid + 0.5f : 1.f/(1.f + __expf(-hid));
        float a = 1.f - z;
        A *= a;
        B = a*B + z*tl;
    }
    const size_t idx = ((size_t)n*NSEG + s)*DI + c;
    Aseg[idx] = A; Bseg[idx] = B;
}

__global__ __launch_bounds__(64) void scan_p2(const float* __restrict__ Aseg,
        const float* __restrict__ Bseg, float* __restrict__ Pseg) {
    const int c = blockIdx.x*64 + threadIdx.x;
    const int n = blockIdx.y;
    float P = 0.f;
    for (int s = 0; s < NSEG; ++s) {
        const size_t idx = ((size_t)n*NSEG + s)*DI + c;
        Pseg[idx] = P;
        P = Aseg[idx]*P + Bseg[idx];
    }
}

__global__ __launch_bounds__(64) void scan_p3(bf16* __restrict__ G,
        const float* __restrict__ Pseg, int dir) {
    const int c = blockIdx.x*64 + threadIdx.x;
    const int s = blockIdx.y;
    const int n = blockIdx.z;
    bf16* base = G + (size_t)n*SEQ*(2*DI) + c;
    float h = Pseg[((size_t)n*NSEG + s)*DI + c];
    #pragma unroll 4
    for (int u = 0; u < SEGLEN; ++u) {
        const int t = dir ? (SEQ-1 - (s*SEGLEN + u)) : (s*SEGLEN + u);
        bf16* p = base + (size_t)t*(2*DI);
        float hid = b2f(p[0]), gate = b2f(p[DI]);
        float z  = 1.f/(1.f + __expf(-gate));
        float tl = hid >= 0.f ? hid + 0.5f : 1.f/(1.f + __expf(-hid));
        h = (1.f - z)*h + z*tl;
        p[0] = f2b(h);
    }
}

// ---------------- small weight transpose: dual-dtype in, bf16 out ----------------
__global__ void transpose_kernel(const void* __restrict__ src, bf16* __restrict__ dst,
                                 int R, int C, const int* __restrict__ flag) {
    const int f32 = *flag;
    int idx = blockIdx.x*256 + threadIdx.x;
    if (idx >= R*C) return;
    int r = idx / C, c = idx - r*C;
    dst[(size_t)c*R + r] = f2b(ldin(src, idx, f32));
}

// ---------------- 128x128 bf16 MFMA GEMM with XOR-swizzled LDS ----------------
// LDS tile: 128 rows x 64 shorts. Logical 16B-block l of row r stored at
// physical block (l ^ (r&7)) -> uniform bank usage on ds_read_b128 (8 lanes/group).
// MODE 0: store bf16; 1: +resid dual; 2: +bias gelu bf16; 3: +bias +resid dual
template<int MODE>
__global__ __launch_bounds__(256, 2) void gemm_kernel(
        const bf16* __restrict__ A, int lda,
        const bf16* __restrict__ Bt,
        void* __restrict__ C, int ldc, int K, size_t row_off,
        const void* __restrict__ bias, const void* __restrict__ resid,
        const int* __restrict__ flag) {
    __shared__ __align__(16) short lsA[128*64];
    __shared__ __align__(16) short lsB[128*64];
    const int tid  = threadIdx.x;
    const int tn0  = blockIdx.x * 128;
    const int tm0  = blockIdx.y * 128;
    const int lane = tid & 63;
    const int wave = tid >> 6;
    const int wm = (wave & 1) * 64;
    const int wn = (wave >> 1) * 64;
    const int row16 = lane & 15;
    const int quad  = lane >> 4;
    const int r7    = row16 & 7;           // row&7 for all fragment rows

    floatx4 acc[4][4];
    #pragma unroll
    for (int i = 0; i < 4; ++i)
        #pragma unroll
        for (int j = 0; j < 4; ++j)
            acc[i][j] = (floatx4){0.f, 0.f, 0.f, 0.f};

    // staging swizzle constants (per-thread, loop-invariant)
    const int so_row = tid >> 3;                 // row within a 32-row slab
    const int so_pb  = tid & 7;                  // physical 16B block
    const int so_lb  = so_pb ^ (so_row & 7);     // logical 16B block

    for (int k0 = 0; k0 < K; k0 += 64) {
        const char* Ab = (const char*)(A + (size_t)tm0*lda + k0);
        const char* Bb = (const char*)(Bt + (size_t)tn0*K + k0);
        #pragma unroll
        for (int it = 0; it < 4; ++it) {
            int row = it*32 + so_row;
            gl2lds16(Ab + (size_t)row*((size_t)lda*2) + so_lb*16,
                     (char*)lsA + row*128 + so_pb*16);
        }
        #pragma unroll
        for (int it = 0; it < 4; ++it) {
            int row = it*32 + so_row;
            gl2lds16(Bb + (size_t)row*((size_t)K*2) + so_lb*16,
                     (char*)lsB + row*128 + so_pb*16);
        }
        __syncthreads();
        #pragma unroll
        for (int kk = 0; kk < 64; kk += 32) {
            const int lb = (kk >> 3) + quad;          // logical block
            const int pb = (lb ^ r7) * 8;             // physical short offset
            short8 af[4], bfr[4];
            #pragma unroll
            for (int i = 0; i < 4; ++i)
                af[i] = *(const short8*)(lsA + (wm + i*16 + row16)*64 + pb);
            #pragma unroll
            for (int j = 0; j < 4; ++j)
                bfr[j] = *(const short8*)(lsB + (wn + j*16 + row16)*64 + pb);
            #pragma unroll
            for (int i = 0; i < 4; ++i)
                #pragma unroll
                for (int j = 0; j < 4; ++j)
                    acc[i][j] = __builtin_amdgcn_mfma_f32_16x16x32_bf16(af[i], bfr[j], acc[i][j], 0, 0, 0);
        }
        __syncthreads();
    }

    const int f32 = (MODE == 0) ? 0 : *flag;
    #pragma unroll
    for (int i = 0; i < 4; ++i) {
        #pragma unroll
        for (int j = 0; j < 4; ++j) {
            #pragma unroll
            for (int r = 0; r < 4; ++r) {
                const int gm = tm0 + wm + i*16 + quad*4 + r;
                const int gn = tn0 + wn + j*16 + row16;
                float v = acc[i][j][r];
                if (MODE == 0) {
                    ((bf16*)C)[(size_t)gm*ldc + gn] = f2b(v);
                } else if (MODE == 1) {
                    size_t gi = (row_off + gm)*(size_t)ldc + gn;
                    v += ldin(resid, gi, f32);
                    stout(C, gi, f32, v);
                } else if (MODE == 2) {
                    v += ldin(bias, gn, f32);
                    v = 0.5f*v*(1.f + erff(v*0.70710678118f));
                    ((bf16*)C)[(size_t)gm*ldc + gn] = f2b(v);
                } else {
                    size_t gi = (row_off + gm)*(size_t)ldc + gn;
                    v += ldin(bias, gn, f32) + ldin(resid, gi, f32);
                    stout(C, gi, f32, v);
                }
            }
        }
    }
}

extern "C" void kernel_launch(void* const* d_in, const int* in_sizes, int n_in,
                              void* d_out, int out_size, void* d_ws, size_t ws_size,
                              hipStream_t stream) {
    const void* x       = d_in[0];
    const void* norm_w  = d_in[1];
    const void* norm_b  = d_in[2];
    const void* dw_w    = d_in[3];
    const void* dw_b    = d_in[4];
    const void* whg1    = d_in[5];
    const void* wout1   = d_in[6];
    const void* whg2    = d_in[7];
    const void* wout2   = d_in[8];
    const void* norm2_w = d_in[9];
    const void* norm2_b = d_in[10];
    const void* p1_w    = d_in[11];
    const void* p1_b    = d_in[12];
    const void* p2_w    = d_in[13];
    const void* p2_b    = d_in[14];
    void* out = d_out;
    char* ws = (char*)d_ws;

    const size_t WSZ = 5898240;   // transposed weights (bf16)

    int CH = 16;
    for (;;) {
        size_t need = 256 + WSZ + (size_t)CH * SEQ * 4608;
        if (need <= ws_size || CH == 2) break;
        CH >>= 1;
    }
    const int NC = N_BATCH / CH;
    const int CHROWS = CH * SEQ;

    int* flag = (int*)ws;
    char* wb = ws + 256;
    bf16* WhgT1  = (bf16*)(wb);                  // 1536 x 384
    bf16* WhgT2  = (bf16*)(wb + 1179648);        // 1536 x 384
    bf16* WoutT1 = (bf16*)(wb + 2359296);        // 384 x 768
    bf16* WoutT2 = (bf16*)(wb + 2949120);        // 384 x 768
    bf16* P1T    = (bf16*)(wb + 3538944);        // 1536 x 384
    bf16* P2T    = (bf16*)(wb + 4718592);        // 384 x 1536
    char* dyn = ws + 256 + WSZ;
    bf16* h_ln_c   = (bf16*)(dyn);
    bf16* h_conv_c = (bf16*)(dyn + (size_t)CHROWS*DIM*2);
    bf16* Gbuf     = (bf16*)(dyn + 2*(size_t)CHROWS*DIM*2);
    bf16* mid_ln_c = h_ln_c;
    float* Aseg = (float*)h_ln_c;
    float* Bseg = Aseg + (size_t)CH*NSEG*DI;
    float* Pseg = Bseg + (size_t)CH*NSEG*DI;

    detect_kernel<<<1, 256, 0, stream>>>((const unsigned short*)x, flag);

    transpose_kernel<<<(384*1536+255)/256, 256, 0, stream>>>(whg1, WhgT1, 384, 1536, flag);
    transpose_kernel<<<(384*1536+255)/256, 256, 0, stream>>>(whg2, WhgT2, 384, 1536, flag);
    transpose_kernel<<<(768*384+255)/256, 256, 0, stream>>>(wout1, WoutT1, 768, 384, flag);
    transpose_kernel<<<(768*384+255)/256, 256, 0, stream>>>(wout2, WoutT2, 768, 384, flag);
    transpose_kernel<<<(384*1536+255)/256, 256, 0, stream>>>(p1_w, P1T, 384, 1536, flag);
    transpose_kernel<<<(1536*384+255)/256, 256, 0, stream>>>(p2_w, P2T, 1536, 384, flag);

    for (int pass = 0; pass < 2; ++pass) {
        const bf16* WhgT  = pass ? WhgT2  : WhgT1;
        const bf16* WoutT = pass ? WoutT2 : WoutT1;
        for (int ck = 0; ck < NC; ++ck) {
            const size_t roff = (size_t)ck * CHROWS;
            if (pass == 0 || NC > 1) {
                ln_kernel<<<CHROWS, 64, 0, stream>>>(x, norm_w, norm_b, h_ln_c, roff, flag);
                dwconv_kernel<<<dim3(3, SEQ, CH), 128, 0, stream>>>(h_ln_c, dw_w, dw_b, h_conv_c, flag);
            }
            gemm_kernel<0><<<dim3(1536/128, CHROWS/128), 256, 0, stream>>>(
                h_conv_c, DIM, WhgT, Gbuf, 2*DI, DIM, 0, nullptr, nullptr, flag);
            scan_p1<<<dim3(12, NSEG, CH), 64, 0, stream>>>(Gbuf, Aseg, Bseg, pass);
            scan_p2<<<dim3(12, CH), 64, 0, stream>>>(Aseg, Bseg, Pseg);
            scan_p3<<<dim3(12, NSEG, CH), 64, 0, stream>>>(Gbuf, Pseg, pass);
            const void* resid = pass ? (const void*)out : x;
            gemm_kernel<1><<<dim3(DIM/128, CHROWS/128), 256, 0, stream>>>(
                Gbuf, 2*DI, WoutT, out, DIM, DI, roff, nullptr, resid, flag);
        }
    }

    for (int ck = 0; ck < NC; ++ck) {
        const size_t roff = (size_t)ck * CHROWS;
        ln_kernel<<<CHROWS, 64, 0, stream>>>(out, norm2_w, norm2_b, mid_ln_c, roff, flag);
        gemm_kernel<2><<<dim3(1536/128, CHROWS/128), 256, 0, stream>>>(
            mid_ln_c, DIM, P1T, Gbuf, 1536, DIM, 0, p1_b, nullptr, flag);
        gemm_kernel<3><<<dim3(DIM/128, CHROWS/128), 256, 0, stream>>>(
            Gbuf, 1536, P2T, out, DIM, 1536, roff, p2_b, out, flag);
    }
}